// Round 13
// baseline (343.754 us; speedup 1.0000x reference)
//
#include <hip/hip_runtime.h>
#include <math.h>

typedef unsigned int u32;
typedef unsigned long long u64;

constexpr int N_IMG = 16;
constexpr int C_CLS = 80;
constexpr int H_DIM = 160;
constexpr int W_DIM = 160;
constexpr int L_LOC = H_DIM * W_DIM;   // 25600
constexpr int LC    = L_LOC * C_CLS;   // 2048000
constexpr int K_TOP = 1000;
constexpr int NB    = 1024;            // histogram buckets: (bits-KEY_BASE)>>16
constexpr int CAP   = 2048;            // candidate cap per image (16KB LDS sort)
constexpr int GBUF  = 2048;            // per-block survivor LDS buffer (u64)
constexpr int CHUNK_L = 512;           // locations per block
constexpr int NSEG  = L_LOC / CHUNK_L; // 50 blocks per image
constexpr int CF4   = CHUNK_L / 4;     // 128 float4 per class row (power of 2!)
constexpr int NTOT  = NSEG * N_IMG;    // 800 blocks total (fits 4/CU x 256 CU)
constexpr float THRESH = 0.05f;
constexpr u32 KEY_BASE = 119u << 23;   // 0x3B800000
constexpr float T0     = 0.7f;
constexpr float DELTA  = 0.05f;        // conservative slack in logit space
// buckets >= B_SAFE have lower bound > 0.7f, where spec is provably a superset
constexpr int B_SAFE  = ((0x3F340000u - KEY_BASE) >> 16);  // 948

// ---- workspace layout (bytes); zero node clears [0, WS_KEYS) each call ----
constexpr size_t WS_BAR   = 0;                                   // u32[1] barrier
constexpr size_t WS_CNT   = 64;                                  // u32[16]
constexpr size_t WS_OFLOW = 128;                                 // u32[16]
constexpr size_t WS_GHIST = 512;                                 // 16*1024*4 = 64KB
constexpr size_t WS_KEYS  = WS_GHIST + (size_t)N_IMG * NB * 4;   // 16*2048*8 = 256KB
constexpr int ZERO_WORDS  = (int)(WS_KEYS / 4);                  // 16512

__device__ inline float sigmoidf_acc(float x) { return 1.0f / (1.0f + expf(-x)); }

__device__ inline u32 score_bucket(u32 bits) {
    u32 b = (bits >= KEY_BASE) ? ((bits - KEY_BASE) >> 16) : 0u;
    return b > (u32)(NB - 1) ? (u32)(NB - 1) : b;
}

__device__ inline u32 aload32(const u32* p) {
    return __hip_atomic_load(p, __ATOMIC_RELAXED, __HIP_MEMORY_SCOPE_AGENT);
}
__device__ inline u64 aload64(const u64* p) {
    return __hip_atomic_load(p, __ATOMIC_RELAXED, __HIP_MEMORY_SCOPE_AGENT);
}
__device__ inline void astore64(u64* p, u64 v) {
    __hip_atomic_store(p, v, __ATOMIC_RELAXED, __HIP_MEMORY_SCOPE_AGENT);
}

// bitonic sort of sk[0..n2) descending (pads with 0 above M); barriers inside
__device__ inline void bitonic_desc(u64* sk, u32 M, int tid, int nthr) {
    u32 n2 = 1024; while (n2 < M) n2 <<= 1;
    for (u32 i = tid; i < n2; i += nthr) if (i >= M) sk[i] = 0ull;
    __syncthreads();
    for (u32 k = 2; k <= n2; k <<= 1) {
        for (u32 j = k >> 1; j > 0; j >>= 1) {
            for (u32 i = tid; i < n2; i += nthr) {
                u32 ixj = i ^ j;
                if (ixj > i) {
                    u64 a = sk[i], b = sk[ixj];
                    bool front = ((i & k) == 0);
                    if (front ? (a < b) : (a > b)) { sk[i] = b; sk[ixj] = a; }
                }
            }
            __syncthreads();
        }
    }
}

// decode + write the K output rows for image n
__device__ inline void emit_rows(int n, const u64* sk, u32 cand_slots, const u32* fill,
                                 const float* locations, const float* breg,
                                 const int* isz, float* out, int tid, int nthr) {
    float* ob = out;                                  // boxes  [N,K,4]
    float* os = out + (size_t)N_IMG * K_TOP * 4;      // scores [N,K]
    float* ol = os + (size_t)N_IMG * K_TOP;           // labels [N,K]
    float* ov = ol + (size_t)N_IMG * K_TOP;           // valid  [N,K]
    const float wimg = (float)isz[n * 2 + 1];
    const float himg = (float)isz[n * 2 + 0];
    const float* rn = breg + (size_t)n * 4 * L_LOC;
    for (int k = tid; k < K_TOP; k += nthr) {
        size_t slot = (size_t)n * K_TOP + k;
        if ((u32)k < cand_slots) {
            u64 kk = sk[k];
            u32 vb = (u32)(kk >> 32);
            u32 idx = ~(u32)(kk & 0xFFFFFFFFull);
            float val = __uint_as_float(vb);
            int loc = (int)(idx / (u32)C_CLS);
            int c = (int)(idx - (u32)loc * (u32)C_CLS);
            float lx = locations[loc * 2 + 0], ly = locations[loc * 2 + 1];
            float r0 = rn[0 * L_LOC + loc], r1 = rn[1 * L_LOC + loc];
            float r2 = rn[2 * L_LOC + loc], r3 = rn[3 * L_LOC + loc];
            float x1 = lx - r0, y1 = ly - r1, x2 = lx + r2, y2 = ly + r3;
            x1 = fminf(fmaxf(x1, 0.0f), wimg - 1.0f);
            y1 = fminf(fmaxf(y1, 0.0f), himg - 1.0f);
            x2 = fminf(fmaxf(x2, 0.0f), wimg - 1.0f);
            y2 = fminf(fmaxf(y2, 0.0f), himg - 1.0f);
            float wsz = x2 - x1 + 1.0f, hsz = y2 - y1 + 1.0f;
            bool v = (val > 0.0f) && (wsz >= 0.0f) && (hsz >= 0.0f);  // MIN_SIZE = 0
            float vf = v ? 1.0f : 0.0f;
            ob[slot * 4 + 0] = x1 * vf;
            ob[slot * 4 + 1] = y1 * vf;
            ob[slot * 4 + 2] = x2 * vf;
            ob[slot * 4 + 3] = y2 * vf;
            os[slot] = v ? sqrtf(fmaxf(val, 0.0f)) : 0.0f;
            ol[slot] = (float)(c + 1);
            ov[slot] = vf;
        } else {
            u32 fi = fill ? fill[k - (int)cand_slots] : 0u;
            ob[slot * 4 + 0] = 0.0f; ob[slot * 4 + 1] = 0.0f;
            ob[slot * 4 + 2] = 0.0f; ob[slot * 4 + 3] = 0.0f;
            os[slot] = 0.0f;
            ol[slot] = (float)((int)(fi % (u32)C_CLS) + 1);
            ov[slot] = 0.0f;
        }
    }
}

// strip-based backward scan over lh[NB] with 256 threads; finds the largest
// bucket with suffix >= K_TOP. Outputs: *s_b = bucket+1 (0 = none),
// *s_aux = suffix count at that bucket, *s_total = suffix(0).
// Caller must set *s_b = 0 (+barrier) before calling.
__device__ inline void suffix_cutoff(u32* lh, u32* part, u32* part2,
                                     u32* s_b, u32* s_aux, u32* s_total, int tid) {
    part[tid] = lh[4 * tid] + lh[4 * tid + 1] + lh[4 * tid + 2] + lh[4 * tid + 3];
    __syncthreads();
    u32* src = part; u32* dst = part2;
    for (u32 off = 1; off < 256; off <<= 1) {
        u32 v = src[tid] + ((tid + (int)off < 256) ? src[tid + (int)off] : 0u);
        dst[tid] = v;
        __syncthreads();
        u32* t2 = src; src = dst; dst = t2;
    }
    u32 nxt = (tid < 255) ? src[tid + 1] : 0u;
    u32 s3 = lh[4 * tid + 3] + nxt;
    u32 s2 = lh[4 * tid + 2] + s3;
    u32 s1 = lh[4 * tid + 1] + s2;
    u32 s0 = lh[4 * tid + 0] + s1;
    if (tid == 0) *s_total = s0;
    int lb = -1; u32 lc = 0;
    if (s3 >= (u32)K_TOP)      { lb = 4 * tid + 3; lc = s3; }
    else if (s2 >= (u32)K_TOP) { lb = 4 * tid + 2; lc = s2; }
    else if (s1 >= (u32)K_TOP) { lb = 4 * tid + 1; lc = s1; }
    else if (s0 >= (u32)K_TOP) { lb = 4 * tid + 0; lc = s0; }
    if (lb >= 0) atomicMax(s_b, (u32)(lb + 1));
    __syncthreads();
    if (lb >= 0 && (u32)(lb + 1) == *s_b) *s_aux = lc;
    __syncthreads();
}

// --- kernel 1: zero barrier/cnt/oflow/ghist (poison-safe per-call init) ---
__global__ void zero_kernel(u32* __restrict__ ws32) {
    int i = blockIdx.x * blockDim.x + threadIdx.x;
    if (i < ZERO_WORDS) ws32[i] = 0u;
}

// --- kernel 2 (fused): stream+mask+score+hist | grid-barrier | distributed
//     filter | grid-barrier | per-image sort+emit (16 finisher blocks) ---
__global__ __launch_bounds__(256, 4) void fused_kernel(
        const float* __restrict__ cls, const float* __restrict__ ctr,
        const float* __restrict__ locations, const float* __restrict__ breg,
        const int* __restrict__ isz, float* __restrict__ out,
        u32* __restrict__ ws32) {
    __shared__ __align__(16) float xm[CHUNK_L];      // 2KB
    __shared__ float sct[CHUNK_L];                   // 2KB
    __shared__ u64 sbuf[GBUF];                       // 16KB (reused as sort buf)
    __shared__ u32 lh[NB];                           // 4KB
    __shared__ u32 part[256], part2[256];            // 2KB
    __shared__ u32 fill[K_TOP];                      // 4KB
    __shared__ u32 s_lcnt, s_lof, s_b, s_aux, s_total, s_base;

    u32* bar   = ws32 + WS_BAR / 4;
    u32* cntg  = ws32 + WS_CNT / 4;
    u32* oflow = ws32 + WS_OFLOW / 4;
    u32* ghist = ws32 + WS_GHIST / 4;
    u64* keys  = (u64*)(ws32 + WS_KEYS / 4);

    const int tid = threadIdx.x;
    const u32 n = blockIdx.y, seg = blockIdx.x;
    const u32 lbase = seg * (u32)CHUNK_L;

    // ---------------- P1: stream + survivor scoring + hist ----------------
    for (int i = tid; i < NB; i += 256) lh[i] = 0u;
    if (tid == 0) { s_lcnt = 0; s_lof = 0; }
    for (int i = tid; i < CHUNK_L; i += 256) {
        float s = sigmoidf_acc(ctr[(size_t)n * L_LOC + lbase + i]);
        sct[i] = s;
        float t = T0 / s;                   // need sigmoid(x) >= t for score >= T0
        xm[i] = (t >= 1.0f) ? 3.0e38f : (logf(t / (1.0f - t)) - DELTA);
    }
    __syncthreads();
    const float* base = cls + (size_t)n * LC + lbase;
    u32 mk[5] = {0u, 0u, 0u, 0u, 0u};                // 40 f4 -> 160 mask bits
#pragma unroll
    for (int g = 0; g < 8; ++g) {
        float4 v[5]; u32 l4a[5];
#pragma unroll
        for (int k2 = 0; k2 < 5; ++k2) {
            int q = g * 5 + k2;
            u32 f = (u32)q * 256u + (u32)tid;        // f4 index in [0, 10240)
            u32 c = f >> 7, l4 = f & 127u;           // CF4 = 128 -> shifts
            l4a[k2] = l4;
            v[k2] = *reinterpret_cast<const float4*>(base + (size_t)c * L_LOC + l4 * 4u);
        }
#pragma unroll
        for (int k2 = 0; k2 < 5; ++k2) {
            int q = g * 5 + k2;
            float4 m4 = *reinterpret_cast<const float4*>(&xm[l4a[k2] * 4u]);
            u32 nib = (v[k2].x >= m4.x ? 1u : 0u) | (v[k2].y >= m4.y ? 2u : 0u)
                    | (v[k2].z >= m4.z ? 4u : 0u) | (v[k2].w >= m4.w ? 8u : 0u);
            mk[q >> 3] |= nib << ((q & 7) * 4);
        }
    }
#pragma unroll
    for (int w = 0; w < 5; ++w) {
        u32 bits = mk[w];
        while (bits) {
            u32 b = (u32)__ffs(bits) - 1u; bits &= bits - 1u;
            u32 q = (u32)w * 8u + (b >> 2), j = b & 3u;
            u32 f = q * 256u + (u32)tid;
            u32 c = f >> 7, l4 = f & 127u;
            u32 li = l4 * 4u + j, loc = lbase + li;
            float x = base[(size_t)c * L_LOC + li];  // L3-resident re-read
            float s = sigmoidf_acc(x);               // exact reference formula
            float scr = s * sct[li];
            u32 sb = __float_as_uint(scr);
            atomicAdd(&lh[score_bucket(sb)], 1u);
            u32 p = atomicAdd(&s_lcnt, 1u);
            if (p < (u32)GBUF)
                sbuf[p] = ((u64)sb << 32) | (u32)(~(loc * (u32)C_CLS + c));
            else s_lof = 1u;
        }
    }
    __syncthreads();
    const u32 m_ = s_lcnt > (u32)GBUF ? (u32)GBUF : s_lcnt;
    for (int b = tid; b < NB; b += 256) {
        u32 v = lh[b];
        if (v) atomicAdd(&ghist[n * NB + b], v);
    }
    if (tid == 0 && (s_lof || s_lcnt > (u32)GBUF)) atomicOr(&oflow[n], 1u);

    // ---------------- grid barrier 1 ----------------
    __syncthreads();
    if (tid == 0) {
        __threadfence();
        atomicAdd(bar, 1u);
        while (__hip_atomic_load(bar, __ATOMIC_ACQUIRE, __HIP_MEMORY_SCOPE_AGENT)
               < (u32)NTOT)
            __builtin_amdgcn_s_sleep(8);
    }
    __syncthreads();

    // ---- P2: every block derives cutoff from global hist; filters own sbuf ----
    for (int i = tid; i < NB; i += 256) lh[i] = aload32(&ghist[n * NB + i]);
    if (tid == 0) { s_b = 0; s_aux = 0; }
    __syncthreads();
    suffix_cutoff(lh, part, part2, &s_b, &s_aux, &s_total, tid);
    const u32 bstar = s_b;                 // bucket+1; 0 = none
    const u32 cnt_at = s_aux;
    const u32 ofl = aload32(&oflow[n]);
    const bool fastok = (ofl == 0u) && (bstar != 0u) &&
                        ((bstar - 1u) >= (u32)B_SAFE) && (cnt_at <= (u32)CAP);
    if (fastok) {
        const u32 keymin = KEY_BASE + ((bstar - 1u) << 16);
        if (tid == 0) s_aux = 0;
        __syncthreads();
        u32 mymatch = 0;
        for (u32 i = tid; i < m_; i += 256)
            if ((u32)(sbuf[i] >> 32) >= keymin) mymatch++;
        if (mymatch) atomicAdd(&s_aux, mymatch);
        __syncthreads();
        if (tid == 0) {
            s_base = s_aux ? atomicAdd(&cntg[n], s_aux) : 0u;
            s_aux = 0;
        }
        __syncthreads();
        const u32 gb = s_base;
        for (u32 i = tid; i < m_; i += 256) {
            u64 e = sbuf[i];
            if ((u32)(e >> 32) >= keymin) {
                u32 p = atomicAdd(&s_aux, 1u);
                u32 pos = gb + p;
                if (pos < (u32)CAP) astore64(&keys[(size_t)n * CAP + pos], e);
            }
        }
    }

    // ---------------- grid barrier 2 ----------------
    __syncthreads();
    if (tid == 0) {
        __threadfence();
        atomicAdd(bar, 1u);
        while (__hip_atomic_load(bar, __ATOMIC_ACQUIRE, __HIP_MEMORY_SCOPE_AGENT)
               < 2u * (u32)NTOT)
            __builtin_amdgcn_s_sleep(8);
    }
    __syncthreads();

    // ---------------- P3: finisher blocks only ----------------
    if (seg != 0u) return;
    u64* sk = sbuf;                                  // reuse 16KB LDS
    if (fastok) {
        u32 Mk = aload32(&cntg[n]);                  // == cnt_at <= CAP, >= K
        if (Mk > (u32)CAP) Mk = (u32)CAP;
        for (u32 i = tid; i < Mk; i += 256) sk[i] = aload64(&keys[(size_t)n * CAP + i]);
        bitonic_desc(sk, Mk, tid, 256);
        emit_rows(n, sk, (u32)K_TOP, nullptr, locations, breg, isz, out, tid, 256);
        return;
    }
    // ---------- SLOW path (gated; full per-image pipeline; 256 threads) ----------
    const float* cls_n = cls + (size_t)n * LC;
    const float* ctr_n = ctr + (size_t)n * L_LOC;
    for (int i = tid; i < NB; i += 256) lh[i] = 0u;
    if (tid == 0) { s_b = 0; s_aux = 0; s_lcnt = 0; s_total = 0; s_base = 0; }
    __syncthreads();
    for (u32 f = tid; f < (u32)LC; f += 256) {
        float s = sigmoidf_acc(cls_n[f]);
        if (s > THRESH) {
            float scr = s * sigmoidf_acc(ctr_n[f % (u32)L_LOC]);
            atomicAdd(&lh[score_bucket(__float_as_uint(scr))], 1u);
        }
    }
    __syncthreads();
    suffix_cutoff(lh, part, part2, &s_b, &s_aux, &s_total, tid);
    const u32 total = s_total;
    const u32 keymin = (s_b != 0u) ? (KEY_BASE + ((s_b - 1u) << 16)) : 0u;
    __syncthreads();
    for (u32 f = tid; f < (u32)LC; f += 256) {
        float s = sigmoidf_acc(cls_n[f]);
        if (s > THRESH) {
            u32 loc = f % (u32)L_LOC;
            u32 c = f / (u32)L_LOC;
            float scr = s * sigmoidf_acc(ctr_n[loc]);
            u32 bits = __float_as_uint(scr);
            if (bits >= keymin) {
                u32 p = atomicAdd(&s_lcnt, 1u);
                if (p < (u32)CAP)
                    sk[p] = ((u64)bits << 32) | (u32)(~(loc * (u32)C_CLS + c));
            }
        }
    }
    __syncthreads();
    u32 M = s_lcnt > (u32)CAP ? (u32)CAP : s_lcnt;
    u32 cand_slots = total < (u32)K_TOP ? total : (u32)K_TOP;
    if (total < (u32)K_TOP) {                        // fallback fill list
        const u32 need = (u32)K_TOP - total;
        const int lane = tid & 63, wv = tid >> 6;
        if (tid == 0) s_base = 0;                    // filled counter
        __syncthreads();
        for (u32 basei = 0; basei < (u32)LC; basei += 256) {
            u32 idx = basei + tid;
            u32 flag = 0;
            if (idx < (u32)LC) {
                u32 loc = idx / (u32)C_CLS;
                u32 c = idx - loc * (u32)C_CLS;
                flag = (sigmoidf_acc(cls_n[(size_t)c * L_LOC + loc]) > THRESH) ? 0u : 1u;
            }
            u64 bm = __ballot(flag != 0u);
            if (lane == 0) part[wv] = (u32)__popcll(bm);
            __syncthreads();
            u32 prior = s_base;
            for (int w2 = 0; w2 < wv; ++w2) prior += part[w2];
            u32 mypos = prior + (u32)__popcll(bm & (((u64)1 << lane) - 1ull));
            if (flag && mypos < need) fill[mypos] = idx;
            __syncthreads();
            if (tid == 0) s_base += part[0] + part[1] + part[2] + part[3];
            __syncthreads();
            if (s_base >= need) break;
        }
    }
    bitonic_desc(sk, M, tid, 256);
    emit_rows(n, sk, cand_slots, fill, locations, breg, isz, out, tid, 256);
}

extern "C" void kernel_launch(void* const* d_in, const int* in_sizes, int n_in,
                              void* d_out, int out_size, void* d_ws, size_t ws_size,
                              hipStream_t stream) {
    const float* locations = (const float*)d_in[0];
    const float* cls       = (const float*)d_in[1];
    const float* breg      = (const float*)d_in[2];
    const float* ctr       = (const float*)d_in[3];
    const int*   isz       = (const int*)d_in[4];
    float* out = (float*)d_out;
    u32* ws32 = (u32*)d_ws;

    zero_kernel<<<(ZERO_WORDS + 255) / 256, 256, 0, stream>>>(ws32);
    fused_kernel<<<dim3(NSEG, N_IMG), 256, 0, stream>>>(
        cls, ctr, locations, breg, isz, out, ws32);
}

// Round 14
// 236.981 us; speedup vs baseline: 1.4506x; 1.4506x over previous
//
#include <hip/hip_runtime.h>
#include <math.h>

typedef unsigned int u32;
typedef unsigned long long u64;

constexpr int N_IMG = 16;
constexpr int C_CLS = 80;
constexpr int H_DIM = 160;
constexpr int W_DIM = 160;
constexpr int L_LOC = H_DIM * W_DIM;   // 25600
constexpr int LC    = L_LOC * C_CLS;   // 2048000
constexpr int K_TOP = 1000;
constexpr int NB    = 1024;            // histogram buckets: (bits-KEY_BASE)>>16
constexpr int CAP   = 2048;            // candidate cap per image (16KB LDS)
constexpr int GBUF  = 1024;            // per-block survivor buffer (u64)
constexpr int CHUNK_L = 320;           // locations per block (r12-proven geometry)
constexpr int NSEG  = L_LOC / CHUNK_L; // 80 blocks per image
constexpr int CF4   = CHUNK_L / 4;     // 80 float4 per class row
constexpr int SPAN  = 80;              // max buckets above B_SAFE (1024-948=76)
constexpr float THRESH = 0.05f;
constexpr u32 KEY_BASE = 119u << 23;   // 0x3B800000
constexpr float T0     = 0.7f;
constexpr float DELTA  = 0.05f;        // conservative slack in logit space
// buckets >= B_SAFE have lower bound > 0.7f, where spec is provably a superset
constexpr int B_SAFE  = ((0x3F340000u - KEY_BASE) >> 16);  // 948

// ---- workspace layout (bytes); zero node clears only arrive[16] ----
constexpr size_t WS_ARR  = 0;                                  // u32[16]
constexpr size_t WS_BCNT = 64;                                 // u32[16*80]
constexpr size_t WS_SPEC = 8192;                               // u64[16*80*1024] = 10MB

__device__ inline float sigmoidf_acc(float x) { return 1.0f / (1.0f + expf(-x)); }

__device__ inline u32 score_bucket(u32 bits) {
    u32 b = (bits >= KEY_BASE) ? ((bits - KEY_BASE) >> 16) : 0u;
    return b > (u32)(NB - 1) ? (u32)(NB - 1) : b;
}

__device__ inline u32 aload32(const u32* p) {
    return __hip_atomic_load(p, __ATOMIC_RELAXED, __HIP_MEMORY_SCOPE_AGENT);
}
__device__ inline u64 aload64(const u64* p) {
    return __hip_atomic_load(p, __ATOMIC_RELAXED, __HIP_MEMORY_SCOPE_AGENT);
}

// bitonic sort (slow path only)
__device__ inline void bitonic_desc(u64* sk, u32 M, int tid, int nthr) {
    u32 n2 = 1024; while (n2 < M) n2 <<= 1;
    for (u32 i = tid; i < n2; i += nthr) if (i >= M) sk[i] = 0ull;
    __syncthreads();
    for (u32 k = 2; k <= n2; k <<= 1) {
        for (u32 j = k >> 1; j > 0; j >>= 1) {
            for (u32 i = tid; i < n2; i += nthr) {
                u32 ixj = i ^ j;
                if (ixj > i) {
                    u64 a = sk[i], b = sk[ixj];
                    bool front = ((i & k) == 0);
                    if (front ? (a < b) : (a > b)) { sk[i] = b; sk[ixj] = a; }
                }
            }
            __syncthreads();
        }
    }
}

// decode one candidate key and write its output row at rank k
__device__ inline void emit_one(int n, u64 kk, int k,
                                const float* locations, const float* breg,
                                const int* isz, float* out) {
    float* ob = out;                                  // boxes  [N,K,4]
    float* os = out + (size_t)N_IMG * K_TOP * 4;      // scores [N,K]
    float* ol = os + (size_t)N_IMG * K_TOP;           // labels [N,K]
    float* ov = ol + (size_t)N_IMG * K_TOP;           // valid  [N,K]
    const float wimg = (float)isz[n * 2 + 1];
    const float himg = (float)isz[n * 2 + 0];
    const float* rn = breg + (size_t)n * 4 * L_LOC;
    size_t slot = (size_t)n * K_TOP + k;
    u32 vb = (u32)(kk >> 32);
    u32 idx = ~(u32)(kk & 0xFFFFFFFFull);
    float val = __uint_as_float(vb);
    int loc = (int)(idx / (u32)C_CLS);
    int c = (int)(idx - (u32)loc * (u32)C_CLS);
    float lx = locations[loc * 2 + 0], ly = locations[loc * 2 + 1];
    float r0 = rn[0 * L_LOC + loc], r1 = rn[1 * L_LOC + loc];
    float r2 = rn[2 * L_LOC + loc], r3 = rn[3 * L_LOC + loc];
    float x1 = lx - r0, y1 = ly - r1, x2 = lx + r2, y2 = ly + r3;
    x1 = fminf(fmaxf(x1, 0.0f), wimg - 1.0f);
    y1 = fminf(fmaxf(y1, 0.0f), himg - 1.0f);
    x2 = fminf(fmaxf(x2, 0.0f), wimg - 1.0f);
    y2 = fminf(fmaxf(y2, 0.0f), himg - 1.0f);
    float wsz = x2 - x1 + 1.0f, hsz = y2 - y1 + 1.0f;
    bool v = (val > 0.0f) && (wsz >= 0.0f) && (hsz >= 0.0f);  // MIN_SIZE = 0
    float vf = v ? 1.0f : 0.0f;
    ob[slot * 4 + 0] = x1 * vf;
    ob[slot * 4 + 1] = y1 * vf;
    ob[slot * 4 + 2] = x2 * vf;
    ob[slot * 4 + 3] = y2 * vf;
    os[slot] = v ? sqrtf(fmaxf(val, 0.0f)) : 0.0f;
    ol[slot] = (float)(c + 1);
    ov[slot] = vf;
}

// decode + write K rows from a sorted array (slow path)
__device__ inline void emit_rows(int n, const u64* sk, u32 cand_slots, const u32* fill,
                                 const float* locations, const float* breg,
                                 const int* isz, float* out, int tid, int nthr) {
    float* ob = out;
    float* os = out + (size_t)N_IMG * K_TOP * 4;
    float* ol = os + (size_t)N_IMG * K_TOP;
    float* ov = ol + (size_t)N_IMG * K_TOP;
    for (int k = tid; k < K_TOP; k += nthr) {
        size_t slot = (size_t)n * K_TOP + k;
        if ((u32)k < cand_slots) {
            emit_one(n, sk[k], k, locations, breg, isz, out);
        } else {
            u32 fi = fill ? fill[k - (int)cand_slots] : 0u;
            ob[slot * 4 + 0] = 0.0f; ob[slot * 4 + 1] = 0.0f;
            ob[slot * 4 + 2] = 0.0f; ob[slot * 4 + 3] = 0.0f;
            os[slot] = 0.0f;
            ol[slot] = (float)((int)(fi % (u32)C_CLS) + 1);
            ov[slot] = 0.0f;
        }
    }
}

// backward strip scan over lh[NB], 256 threads. *s_b = bucket+1 (0 = none),
// *s_aux = suffix count at that bucket, *s_total = suffix(0).
// Caller must zero *s_b (+barrier) first.
__device__ inline void suffix_cutoff(u32* lh, u32* part, u32* part2,
                                     u32* s_b, u32* s_aux, u32* s_total, int tid) {
    part[tid] = lh[4 * tid] + lh[4 * tid + 1] + lh[4 * tid + 2] + lh[4 * tid + 3];
    __syncthreads();
    u32* src = part; u32* dst = part2;
    for (u32 off = 1; off < 256; off <<= 1) {
        u32 v = src[tid] + ((tid + (int)off < 256) ? src[tid + (int)off] : 0u);
        dst[tid] = v;
        __syncthreads();
        u32* t2 = src; src = dst; dst = t2;
    }
    u32 nxt = (tid < 255) ? src[tid + 1] : 0u;
    u32 s3 = lh[4 * tid + 3] + nxt;
    u32 s2 = lh[4 * tid + 2] + s3;
    u32 s1 = lh[4 * tid + 1] + s2;
    u32 s0 = lh[4 * tid + 0] + s1;
    if (tid == 0) *s_total = s0;
    int lb = -1; u32 lc = 0;
    if (s3 >= (u32)K_TOP)      { lb = 4 * tid + 3; lc = s3; }
    else if (s2 >= (u32)K_TOP) { lb = 4 * tid + 2; lc = s2; }
    else if (s1 >= (u32)K_TOP) { lb = 4 * tid + 1; lc = s1; }
    else if (s0 >= (u32)K_TOP) { lb = 4 * tid + 0; lc = s0; }
    if (lb >= 0) atomicMax(s_b, (u32)(lb + 1));
    __syncthreads();
    if (lb >= 0 && (u32)(lb + 1) == *s_b) *s_aux = lc;
    __syncthreads();
}

// flat spec access: global candidate index g -> segment via binsearch on pseg
__device__ inline u64 spec_load(const u64* spn, const u32* pseg, u32 g) {
    u32 lo = 0, hi = NSEG;
    while (hi - lo > 1u) { u32 mid = (lo + hi) >> 1; if (pseg[mid] <= g) lo = mid; else hi = mid; }
    return aload64(&spn[(size_t)lo * GBUF + (g - pseg[lo])]);
}

// --- kernel 1: zero the 16 arrival counters (poison-safe per-call init) ---
__global__ void zero_kernel(u32* __restrict__ ws32) {
    if (threadIdx.x < 16) ws32[WS_ARR / 4 + threadIdx.x] = 0u;
}

// --- kernel 2 (fused): r12 stream+score+segment write, then LAST-BLOCK-per-image
//     finisher: hist -> cutoff -> bucket-grouped place -> rank -> direct emit ---
__global__ __launch_bounds__(256) void fused_kernel(
        const float* __restrict__ cls, const float* __restrict__ ctr,
        const float* __restrict__ locations, const float* __restrict__ breg,
        const int* __restrict__ isz, float* __restrict__ out,
        u32* __restrict__ ws32) {
    __shared__ __align__(16) float xm[CHUNK_L];
    __shared__ float sct[CHUNK_L];
    __shared__ u64 sbuf[GBUF];                        // P1 survivors; slow-path fill overlay
    __shared__ u32 lh[NB];
    __shared__ u32 part[256], part2[256];
    __shared__ u32 segc[NSEG];
    __shared__ u32 pseg[NSEG + 1];
    __shared__ u32 sfxl[SPAN + 1];
    __shared__ u32 bkc[SPAN];
    __shared__ u64 sk[CAP];
    __shared__ u32 s_lcnt, s_lof, s_fin, s_gof, s_b, s_aux, s_total, s_base;

    u32* arrive = ws32 + WS_ARR / 4;
    u32* bcnt   = ws32 + WS_BCNT / 4;
    u64* spec   = (u64*)(ws32 + WS_SPEC / 4);

    const int tid = threadIdx.x;
    const u32 n = blockIdx.y, seg = blockIdx.x;
    const u32 lbase = seg * (u32)CHUNK_L;

    // ---------------- P1: stream + survivor scoring (r12-proven) ----------------
    if (tid == 0) { s_lcnt = 0; s_lof = 0; }
    for (int i = tid; i < CHUNK_L; i += 256) {
        float s = sigmoidf_acc(ctr[(size_t)n * L_LOC + lbase + i]);
        sct[i] = s;
        float t = T0 / s;                   // need sigmoid(x) >= t for score >= T0
        xm[i] = (t >= 1.0f) ? 3.0e38f : (logf(t / (1.0f - t)) - DELTA);
    }
    __syncthreads();
    const float* base = cls + (size_t)n * LC + lbase;
    u32 m0 = 0u, m1 = 0u, m2 = 0u, m3 = 0u;
#pragma unroll
    for (int g = 0; g < 5; ++g) {
        float4 v[5]; u32 l4a[5];
#pragma unroll
        for (int k = 0; k < 5; ++k) {
            int q = g * 5 + k;
            u32 f = (u32)q * 256u + (u32)tid;        // f4 index in [0, 6400)
            u32 c = f / (u32)CF4;
            u32 l4 = f - c * (u32)CF4;
            l4a[k] = l4;
            v[k] = *reinterpret_cast<const float4*>(base + (size_t)c * L_LOC + l4 * 4u);
        }
#pragma unroll
        for (int k = 0; k < 5; ++k) {
            int q = g * 5 + k;
            float4 m4 = *reinterpret_cast<const float4*>(&xm[l4a[k] * 4u]);
            u32 nib = (v[k].x >= m4.x ? 1u : 0u) | (v[k].y >= m4.y ? 2u : 0u)
                    | (v[k].z >= m4.z ? 4u : 0u) | (v[k].w >= m4.w ? 8u : 0u);
            u32 sh = (u32)(q & 7) * 4u;
            if ((q >> 3) == 0) m0 |= nib << sh;
            else if ((q >> 3) == 1) m1 |= nib << sh;
            else if ((q >> 3) == 2) m2 |= nib << sh;
            else m3 |= nib << sh;
        }
    }
    u32 words[4] = {m0, m1, m2, m3};
#pragma unroll
    for (int w = 0; w < 4; ++w) {
        u32 bits = words[w];
        while (bits) {
            u32 b = (u32)__ffs(bits) - 1u; bits &= bits - 1u;
            u32 q = (u32)w * 8u + (b >> 2), j = b & 3u;
            u32 f = q * 256u + (u32)tid;
            u32 c = f / (u32)CF4;
            u32 l4 = f - c * (u32)CF4;
            u32 li = l4 * 4u + j, loc = lbase + li;
            float x = base[(size_t)c * L_LOC + li];  // L3-resident re-read
            float s = sigmoidf_acc(x);               // exact reference formula
            float scr = s * sct[li];
            u32 sb = __float_as_uint(scr);
            u32 p = atomicAdd(&s_lcnt, 1u);
            if (p < (u32)GBUF)
                sbuf[p] = ((u64)sb << 32) | (u32)(~(loc * (u32)C_CLS + c));
            else s_lof = 1u;
        }
    }
    __syncthreads();
    const u32 m_ = s_lcnt > (u32)GBUF ? (u32)GBUF : s_lcnt;
    u64* sp0 = spec + ((size_t)n * NSEG + seg) * GBUF;
    for (u32 i = tid; i < m_; i += 256) sp0[i] = sbuf[i];
    if (tid == 0)
        bcnt[n * NSEG + seg] = m_ | ((s_lof || s_lcnt > (u32)GBUF) ? 0x80000000u : 0u);

    // -------------- arrival: last block of image n becomes finisher --------------
    __threadfence();
    __syncthreads();
    if (tid == 0) s_fin = (atomicAdd(&arrive[n], 1u) == (u32)(NSEG - 1)) ? 1u : 0u;
    __syncthreads();
    if (!s_fin) return;
    __threadfence();                       // acquire side

    // ---------------- finisher: segc, prefix, hist ----------------
    if (tid == 0) { s_gof = 0; s_b = 0; s_aux = 0; s_total = 0; }
    __syncthreads();
    if (tid < NSEG) {
        u32 v = aload32(&bcnt[n * NSEG + tid]);
        segc[tid] = v & 0x7FFFFFFFu;
        if (v & 0x80000000u) atomicOr(&s_gof, 1u);
    }
    for (int i = tid; i < NB; i += 256) lh[i] = 0u;
    __syncthreads();
    if (tid == 0) {
        u32 a = 0;
        for (int s2 = 0; s2 < NSEG; ++s2) { pseg[s2] = a; a += segc[s2]; }
        pseg[NSEG] = a;
    }
    __syncthreads();
    const u32 total = pseg[NSEG];
    const u64* spn = spec + (size_t)n * NSEG * GBUF;
    for (u32 g0 = tid; g0 < total; g0 += 1024) {      // 4-way batched for ILP
        u64 e[4]; u32 ok = 0;
#pragma unroll
        for (int k = 0; k < 4; ++k) {
            u32 g = g0 + (u32)k * 256u;
            if (g < total) { e[k] = spec_load(spn, pseg, g); ok |= 1u << k; }
        }
#pragma unroll
        for (int k = 0; k < 4; ++k)
            if (ok & (1u << k)) atomicAdd(&lh[score_bucket((u32)(e[k] >> 32))], 1u);
    }
    __syncthreads();
    suffix_cutoff(lh, part, part2, &s_b, &s_aux, &s_total, tid);
    const u32 bp1 = s_b;                   // bucket+1; 0 = none
    const u32 cnt_at = s_aux;
    const bool fastok = (s_gof == 0u) && (bp1 != 0u) &&
                        ((bp1 - 1u) >= (u32)B_SAFE) && (cnt_at <= (u32)CAP);
    if (fastok) {
        const u32 bidx = bp1 - 1u;
        const u32 span = (u32)NB - bidx;             // <= 76
        const u32 keymin = KEY_BASE + (bidx << 16);
        // suffix values for buckets [bidx, NB]
        if (tid <= (int)span) {
            u32 a = 0;
            for (u32 q = bidx + (u32)tid; q < (u32)NB; ++q) a += lh[q];
            sfxl[tid] = a;
        }
        if (tid < (int)span) bkc[tid] = 0u;
        __syncthreads();
        // place candidates grouped by bucket (descending bucket = ascending pos)
        for (u32 g0 = tid; g0 < total; g0 += 1024) {
            u64 e[4]; u32 ok = 0;
#pragma unroll
            for (int k = 0; k < 4; ++k) {
                u32 g = g0 + (u32)k * 256u;
                if (g < total) { e[k] = spec_load(spn, pseg, g); ok |= 1u << k; }
            }
#pragma unroll
            for (int k = 0; k < 4; ++k) {
                if (!(ok & (1u << k))) continue;
                u32 bits = (u32)(e[k] >> 32);
                if (bits >= keymin) {
                    u32 t = score_bucket(bits) - bidx;
                    u32 pos = sfxl[t + 1] + atomicAdd(&bkc[t], 1u);
                    if (pos < (u32)CAP) sk[pos] = e[k];
                }
            }
        }
        __syncthreads();
        // rank within bucket + direct emit (keys unique -> ranks unique, complete)
        for (u32 p = tid; p < cnt_at; p += 256) {
            u64 e = sk[p];
            u32 t = score_bucket((u32)(e >> 32)) - bidx;
            u32 r = sfxl[t + 1];
            const u32 qe = sfxl[t];
            for (u32 q = sfxl[t + 1]; q < qe; ++q) r += (sk[q] > e) ? 1u : 0u;
            if (r < (u32)K_TOP)
                emit_one(n, e, (int)r, locations, breg, isz, out);
        }
        return;
    }
    // ---------- SLOW path (gated; full per-image pipeline; 256 threads) ----------
    u32* fill = (u32*)sbuf;                            // overlay (sbuf dead here)
    const float* cls_n = cls + (size_t)n * LC;
    const float* ctr_n = ctr + (size_t)n * L_LOC;
    for (int i = tid; i < NB; i += 256) lh[i] = 0u;
    if (tid == 0) { s_b = 0; s_aux = 0; s_lcnt = 0; s_total = 0; s_base = 0; }
    __syncthreads();
    for (u32 f = tid; f < (u32)LC; f += 256) {
        float s = sigmoidf_acc(cls_n[f]);
        if (s > THRESH) {
            float scr = s * sigmoidf_acc(ctr_n[f % (u32)L_LOC]);
            atomicAdd(&lh[score_bucket(__float_as_uint(scr))], 1u);
        }
    }
    __syncthreads();
    suffix_cutoff(lh, part, part2, &s_b, &s_aux, &s_total, tid);
    const u32 total2 = s_total;
    const u32 keymin = (s_b != 0u) ? (KEY_BASE + ((s_b - 1u) << 16)) : 0u;
    __syncthreads();
    for (u32 f = tid; f < (u32)LC; f += 256) {
        float s = sigmoidf_acc(cls_n[f]);
        if (s > THRESH) {
            u32 loc = f % (u32)L_LOC;
            u32 c = f / (u32)L_LOC;
            float scr = s * sigmoidf_acc(ctr_n[loc]);
            u32 bits = __float_as_uint(scr);
            if (bits >= keymin) {
                u32 p = atomicAdd(&s_lcnt, 1u);
                if (p < (u32)CAP)
                    sk[p] = ((u64)bits << 32) | (u32)(~(loc * (u32)C_CLS + c));
            }
        }
    }
    __syncthreads();
    u32 M = s_lcnt > (u32)CAP ? (u32)CAP : s_lcnt;
    u32 cand_slots = total2 < (u32)K_TOP ? total2 : (u32)K_TOP;
    if (total2 < (u32)K_TOP) {                        // fallback fill list
        const u32 need = (u32)K_TOP - total2;
        const int lane = tid & 63, wv = tid >> 6;
        if (tid == 0) s_base = 0;
        __syncthreads();
        for (u32 basei = 0; basei < (u32)LC; basei += 256) {
            u32 idx = basei + tid;
            u32 flag = 0;
            if (idx < (u32)LC) {
                u32 loc = idx / (u32)C_CLS;
                u32 c = idx - loc * (u32)C_CLS;
                flag = (sigmoidf_acc(cls_n[(size_t)c * L_LOC + loc]) > THRESH) ? 0u : 1u;
            }
            u64 bm = __ballot(flag != 0u);
            if (lane == 0) part[wv] = (u32)__popcll(bm);
            __syncthreads();
            u32 prior = s_base;
            for (int w2 = 0; w2 < wv; ++w2) prior += part[w2];
            u32 mypos = prior + (u32)__popcll(bm & (((u64)1 << lane) - 1ull));
            if (flag && mypos < need) fill[mypos] = idx;
            __syncthreads();
            if (tid == 0) s_base += part[0] + part[1] + part[2] + part[3];
            __syncthreads();
            if (s_base >= need) break;
        }
    }
    bitonic_desc(sk, M, tid, 256);
    emit_rows(n, sk, cand_slots, fill, locations, breg, isz, out, tid, 256);
}

extern "C" void kernel_launch(void* const* d_in, const int* in_sizes, int n_in,
                              void* d_out, int out_size, void* d_ws, size_t ws_size,
                              hipStream_t stream) {
    const float* locations = (const float*)d_in[0];
    const float* cls       = (const float*)d_in[1];
    const float* breg      = (const float*)d_in[2];
    const float* ctr       = (const float*)d_in[3];
    const int*   isz       = (const int*)d_in[4];
    float* out = (float*)d_out;
    u32* ws32 = (u32*)d_ws;

    zero_kernel<<<1, 64, 0, stream>>>(ws32);
    fused_kernel<<<dim3(NSEG, N_IMG), 256, 0, stream>>>(
        cls, ctr, locations, breg, isz, out, ws32);
}

// Round 15
// 60.256 us; speedup vs baseline: 5.7049x; 3.9329x over previous
//
#include <hip/hip_runtime.h>
#include <math.h>

typedef unsigned int u32;
typedef unsigned long long u64;

constexpr int N_IMG = 16;
constexpr int C_CLS = 80;
constexpr int H_DIM = 160;
constexpr int W_DIM = 160;
constexpr int L_LOC = H_DIM * W_DIM;   // 25600
constexpr int LC    = L_LOC * C_CLS;   // 2048000
constexpr int K_TOP = 1000;
constexpr int NB    = 1024;            // histogram buckets: (bits-KEY_BASE)>>16
constexpr int CAP   = 2048;            // candidate cap per image (16KB LDS)
constexpr int GBUF  = 1024;            // per-segment survivor buffer (u64)
constexpr int CHUNK_L = 320;           // locations per megaA block (r12-proven)
constexpr int NSEG  = L_LOC / CHUNK_L; // 80 segments per image
constexpr int CF4   = CHUNK_L / 4;     // 80 float4 per class row
constexpr int SPAN  = 80;              // max buckets above B_SAFE (1024-948=76)
constexpr float THRESH = 0.05f;
constexpr u32 KEY_BASE = 119u << 23;   // 0x3B800000
constexpr float T0     = 0.7f;
constexpr float DELTA  = 0.05f;        // conservative slack in logit space
// buckets >= B_SAFE have lower bound > 0.7f, where spec is provably a superset
constexpr int B_SAFE  = ((0x3F340000u - KEY_BASE) >> 16);  // 948

// ---- workspace layout (bytes); zero node clears ghist only ----
constexpr size_t WS_GHIST = 0;                                  // u32[16*1024] = 64KB
constexpr size_t WS_BCNT  = (size_t)N_IMG * NB * 4;             // u32[16*80]
constexpr size_t WS_SPEC  = WS_BCNT + 8192;                     // u64[16*80*1024] = 10MB
constexpr int ZERO_WORDS  = N_IMG * NB;                         // 16384

__device__ inline float sigmoidf_acc(float x) { return 1.0f / (1.0f + expf(-x)); }

__device__ inline u32 score_bucket(u32 bits) {
    u32 b = (bits >= KEY_BASE) ? ((bits - KEY_BASE) >> 16) : 0u;
    return b > (u32)(NB - 1) ? (u32)(NB - 1) : b;
}

// bitonic sort (slow path only)
__device__ inline void bitonic_desc(u64* sk, u32 M, int tid, int nthr) {
    u32 n2 = 1024; while (n2 < M) n2 <<= 1;
    for (u32 i = tid; i < n2; i += nthr) if (i >= M) sk[i] = 0ull;
    __syncthreads();
    for (u32 k = 2; k <= n2; k <<= 1) {
        for (u32 j = k >> 1; j > 0; j >>= 1) {
            for (u32 i = tid; i < n2; i += nthr) {
                u32 ixj = i ^ j;
                if (ixj > i) {
                    u64 a = sk[i], b = sk[ixj];
                    bool front = ((i & k) == 0);
                    if (front ? (a < b) : (a > b)) { sk[i] = b; sk[ixj] = a; }
                }
            }
            __syncthreads();
        }
    }
}

// decode one candidate key and write its output row at rank k
__device__ inline void emit_one(int n, u64 kk, int k,
                                const float* locations, const float* breg,
                                const int* isz, float* out) {
    float* ob = out;                                  // boxes  [N,K,4]
    float* os = out + (size_t)N_IMG * K_TOP * 4;      // scores [N,K]
    float* ol = os + (size_t)N_IMG * K_TOP;           // labels [N,K]
    float* ov = ol + (size_t)N_IMG * K_TOP;           // valid  [N,K]
    const float wimg = (float)isz[n * 2 + 1];
    const float himg = (float)isz[n * 2 + 0];
    const float* rn = breg + (size_t)n * 4 * L_LOC;
    size_t slot = (size_t)n * K_TOP + k;
    u32 vb = (u32)(kk >> 32);
    u32 idx = ~(u32)(kk & 0xFFFFFFFFull);
    float val = __uint_as_float(vb);
    int loc = (int)(idx / (u32)C_CLS);
    int c = (int)(idx - (u32)loc * (u32)C_CLS);
    float lx = locations[loc * 2 + 0], ly = locations[loc * 2 + 1];
    float r0 = rn[0 * L_LOC + loc], r1 = rn[1 * L_LOC + loc];
    float r2 = rn[2 * L_LOC + loc], r3 = rn[3 * L_LOC + loc];
    float x1 = lx - r0, y1 = ly - r1, x2 = lx + r2, y2 = ly + r3;
    x1 = fminf(fmaxf(x1, 0.0f), wimg - 1.0f);
    y1 = fminf(fmaxf(y1, 0.0f), himg - 1.0f);
    x2 = fminf(fmaxf(x2, 0.0f), wimg - 1.0f);
    y2 = fminf(fmaxf(y2, 0.0f), himg - 1.0f);
    float wsz = x2 - x1 + 1.0f, hsz = y2 - y1 + 1.0f;
    bool v = (val > 0.0f) && (wsz >= 0.0f) && (hsz >= 0.0f);  // MIN_SIZE = 0
    float vf = v ? 1.0f : 0.0f;
    ob[slot * 4 + 0] = x1 * vf;
    ob[slot * 4 + 1] = y1 * vf;
    ob[slot * 4 + 2] = x2 * vf;
    ob[slot * 4 + 3] = y2 * vf;
    os[slot] = v ? sqrtf(fmaxf(val, 0.0f)) : 0.0f;
    ol[slot] = (float)(c + 1);
    ov[slot] = vf;
}

// decode + write K rows from a sorted array (slow path)
__device__ inline void emit_rows(int n, const u64* sk, u32 cand_slots, const u32* fill,
                                 const float* locations, const float* breg,
                                 const int* isz, float* out, int tid, int nthr) {
    float* ob = out;
    float* os = out + (size_t)N_IMG * K_TOP * 4;
    float* ol = os + (size_t)N_IMG * K_TOP;
    float* ov = ol + (size_t)N_IMG * K_TOP;
    for (int k = tid; k < K_TOP; k += nthr) {
        size_t slot = (size_t)n * K_TOP + k;
        if ((u32)k < cand_slots) {
            emit_one(n, sk[k], k, locations, breg, isz, out);
        } else {
            u32 fi = fill ? fill[k - (int)cand_slots] : 0u;
            ob[slot * 4 + 0] = 0.0f; ob[slot * 4 + 1] = 0.0f;
            ob[slot * 4 + 2] = 0.0f; ob[slot * 4 + 3] = 0.0f;
            os[slot] = 0.0f;
            ol[slot] = (float)((int)(fi % (u32)C_CLS) + 1);
            ov[slot] = 0.0f;
        }
    }
}

// --- kernel 1: zero ghist (replays would otherwise accumulate) ---
__global__ void zero_kernel(u32* __restrict__ ws32) {
    int i = blockIdx.x * blockDim.x + threadIdx.x;
    if (i < ZERO_WORDS) ws32[WS_GHIST / 4 + i] = 0u;
}

// --- kernel 2 (hot pass, r12-proven + LDS hist w/ sparse global merge) ---
__global__ __launch_bounds__(256) void megaA_kernel(
        const float* __restrict__ cls, const float* __restrict__ ctr,
        u64* __restrict__ spec, u32* __restrict__ bcnt, u32* __restrict__ ghist) {
    __shared__ __align__(16) float xm[CHUNK_L];
    __shared__ float sct[CHUNK_L];
    __shared__ u64 sbuf[GBUF];
    __shared__ u32 lh[NB];
    __shared__ u32 lcnt, lof;
    const int tid = threadIdx.x;
    const u32 n = blockIdx.y;
    const u32 lbase = blockIdx.x * (u32)CHUNK_L;
    for (int b = tid; b < NB; b += 256) lh[b] = 0u;
    if (tid == 0) { lcnt = 0; lof = 0; }
    // prologue: per-location sigmoid(ctr) and logit threshold
    for (int i = tid; i < CHUNK_L; i += 256) {
        float s = sigmoidf_acc(ctr[(size_t)n * L_LOC + lbase + i]);
        sct[i] = s;
        float t = T0 / s;                   // need sigmoid(x) >= t for score >= T0
        xm[i] = (t >= 1.0f) ? 3.0e38f : (logf(t / (1.0f - t)) - DELTA);
    }
    __syncthreads();
    const float* base = cls + (size_t)n * LC + lbase;
    u32 m0 = 0u, m1 = 0u, m2 = 0u, m3 = 0u;
#pragma unroll
    for (int g = 0; g < 5; ++g) {
        float4 v[5]; u32 l4a[5];
#pragma unroll
        for (int k = 0; k < 5; ++k) {
            int q = g * 5 + k;
            u32 f = (u32)q * 256u + (u32)tid;        // f4 index in [0, 6400)
            u32 c = f / (u32)CF4;
            u32 l4 = f - c * (u32)CF4;
            l4a[k] = l4;
            v[k] = *reinterpret_cast<const float4*>(base + (size_t)c * L_LOC + l4 * 4u);
        }
#pragma unroll
        for (int k = 0; k < 5; ++k) {
            int q = g * 5 + k;
            float4 m4 = *reinterpret_cast<const float4*>(&xm[l4a[k] * 4u]);
            u32 nib = (v[k].x >= m4.x ? 1u : 0u) | (v[k].y >= m4.y ? 2u : 0u)
                    | (v[k].z >= m4.z ? 4u : 0u) | (v[k].w >= m4.w ? 8u : 0u);
            u32 sh = (u32)(q & 7) * 4u;
            if ((q >> 3) == 0) m0 |= nib << sh;
            else if ((q >> 3) == 1) m1 |= nib << sh;
            else if ((q >> 3) == 2) m2 |= nib << sh;
            else m3 |= nib << sh;
        }
    }
    // survivor phase (decoupled from the stream): exact score + LDS hist + append
    u32 words[4] = {m0, m1, m2, m3};
#pragma unroll
    for (int w = 0; w < 4; ++w) {
        u32 bits = words[w];
        while (bits) {
            u32 b = (u32)__ffs(bits) - 1u; bits &= bits - 1u;
            u32 q = (u32)w * 8u + (b >> 2), j = b & 3u;
            u32 f = q * 256u + (u32)tid;
            u32 c = f / (u32)CF4;
            u32 l4 = f - c * (u32)CF4;
            u32 li = l4 * 4u + j, loc = lbase + li;
            float x = base[(size_t)c * L_LOC + li];  // L3-resident re-read
            float s = sigmoidf_acc(x);               // exact reference formula
            float scr = s * sct[li];
            u32 sb = __float_as_uint(scr);
            atomicAdd(&lh[score_bucket(sb)], 1u);
            u32 p = atomicAdd(&lcnt, 1u);
            if (p < (u32)GBUF)
                sbuf[p] = ((u64)sb << 32) | (u32)(~(loc * (u32)C_CLS + c));
            else lof = 1u;
        }
    }
    __syncthreads();
    // sparse merge of per-block hist (only ~50-90 non-zero buckets)
    u32* hn = ghist + (size_t)n * NB;
    for (int b = tid; b < NB; b += 256) {
        u32 v = lh[b];
        if (v) atomicAdd(&hn[b], v);
    }
    const u32 m_ = lcnt > (u32)GBUF ? (u32)GBUF : lcnt;
    u64* sp = spec + ((size_t)n * NSEG + blockIdx.x) * GBUF;
    for (u32 i = tid; i < m_; i += 256) sp[i] = sbuf[i];
    if (tid == 0)
        bcnt[n * NSEG + blockIdx.x] = m_ | ((lof || lcnt > (u32)GBUF) ? 0x80000000u : 0u);
}

// --- kernel 3: FAST finish: ghist -> suffix-scan -> wave-per-segment filter with
//     bucket placement -> within-bucket rank -> direct emit (NO SORT).
//     Inlined SLOW fallback (full rescan; never taken in practice). ---
__global__ __launch_bounds__(1024) void finishC_kernel(
        const u32* __restrict__ ghist, const u64* __restrict__ spec,
        const u32* __restrict__ bcnt, const float* __restrict__ cls,
        const float* __restrict__ ctr, const float* __restrict__ locations,
        const float* __restrict__ breg, const int* __restrict__ isz,
        float* __restrict__ out) {
    __shared__ u32 lh[NB];                 // raw hist -> (destructive) suffix sums
    __shared__ u64 sk[CAP];
    __shared__ u32 fill[K_TOP];
    __shared__ u32 segc[NSEG];
    __shared__ u32 sfxl[SPAN + 1];
    __shared__ u32 bkc[SPAN];
    __shared__ u32 s_b, s_cnt, s_lcnt, s_filled, s_bad;
    const int n = blockIdx.x;
    const int tid = threadIdx.x;
    const int wid = tid >> 6, lane = tid & 63;       // 16 waves of 64
    if (tid == 0) { s_b = 0xFFFFFFFFu; s_lcnt = 0; s_cnt = 0; s_filled = 0; s_bad = 0; }
    lh[tid] = ghist[(size_t)n * NB + tid];
    __syncthreads();
    if (tid < NSEG) {
        u32 v = bcnt[n * NSEG + tid];
        segc[tid] = v & 0x7FFFFFFFu;
        if (v & 0x80000000u) atomicOr(&s_bad, 1u);
    }
    __syncthreads();
    // suffix sums: lh[b] = count with bucket >= b (r12-proven)
    for (u32 off = 1; off < (u32)NB; off <<= 1) {
        u32 add = (tid + off < (u32)NB) ? lh[tid + off] : 0u;
        __syncthreads();
        lh[tid] += add;
        __syncthreads();
    }
    if (lh[tid] >= (u32)K_TOP && (tid == NB - 1 || lh[tid + 1] < (u32)K_TOP)) {
        s_b = (u32)tid; s_cnt = lh[tid];
    }
    __syncthreads();
    const u32 bstar = s_b;
    const u32 cnt_at = s_cnt;
    bool fastok = (s_bad == 0u) && (bstar != 0xFFFFFFFFu) &&
                  (bstar >= (u32)B_SAFE) && (cnt_at <= (u32)CAP);
    const u64* spn = spec + (size_t)n * NSEG * GBUF;
    if (fastok) {
        const u32 span = (u32)NB - bstar;            // <= 76
        const u32 keymin = KEY_BASE + (bstar << 16);
        if (tid <= (int)span) sfxl[tid] = (bstar + (u32)tid < (u32)NB) ? lh[bstar + tid] : 0u;
        if (tid < (int)span) bkc[tid] = 0u;
        __syncthreads();
        // wave-per-segment filter + bucket-grouped placement
        for (int sr = 0; sr < NSEG; sr += 16) {
            int s2 = sr + wid;                        // NSEG % 16 == 0
            u32 cnt = segc[s2];
            const u64* sp = spn + (size_t)s2 * GBUF;
            for (u32 i = lane; i < cnt; i += 64) {
                u64 e = sp[i];
                u32 bits = (u32)(e >> 32);
                if (bits >= keymin) {
                    u32 t = score_bucket(bits) - bstar;
                    u32 pos = sfxl[t + 1] + atomicAdd(&bkc[t], 1u);
                    if (pos < (u32)CAP) sk[pos] = e;
                }
            }
        }
        __syncthreads();
        // within-bucket rank + direct emit (keys unique -> ranks unique, complete)
        for (u32 p = tid; p < cnt_at; p += 1024) {
            u64 e = sk[p];
            u32 t = score_bucket((u32)(e >> 32)) - bstar;
            u32 r = sfxl[t + 1];
            const u32 qe = sfxl[t];
            for (u32 q = sfxl[t + 1]; q < qe; ++q) r += (sk[q] > e) ? 1u : 0u;
            if (r < (u32)K_TOP)
                emit_one(n, e, (int)r, locations, breg, isz, out);
        }
        return;
    }
    // ---------- SLOW path (gated; full per-image pipeline; r12-proven) ----------
    lh[tid] = 0u;
    if (tid == 0) { s_b = 0xFFFFFFFFu; s_lcnt = 0; s_filled = 0; }
    __syncthreads();
    const float* cls_n = cls + (size_t)n * LC;
    const float* ctr_n = ctr + (size_t)n * L_LOC;
    for (u32 f = tid; f < (u32)LC; f += 1024) {
        float s = sigmoidf_acc(cls_n[f]);
        if (s > THRESH) {
            float scr = s * sigmoidf_acc(ctr_n[f % (u32)L_LOC]);
            atomicAdd(&lh[score_bucket(__float_as_uint(scr))], 1u);
        }
    }
    __syncthreads();
    for (u32 off = 1; off < (u32)NB; off <<= 1) {
        u32 add = (tid + off < (u32)NB) ? lh[tid + off] : 0u;
        __syncthreads();
        lh[tid] += add;
        __syncthreads();
    }
    if (lh[tid] >= (u32)K_TOP && (tid == NB - 1 || lh[tid + 1] < (u32)K_TOP))
        s_b = (u32)tid;
    __syncthreads();
    const u32 total = lh[0];
    const u32 keymin = (s_b != 0xFFFFFFFFu) ? (KEY_BASE + (s_b << 16)) : 0u;
    __syncthreads();
    for (u32 f = tid; f < (u32)LC; f += 1024) {
        float s = sigmoidf_acc(cls_n[f]);
        if (s > THRESH) {
            u32 loc = f % (u32)L_LOC;
            u32 c = f / (u32)L_LOC;
            float scr = s * sigmoidf_acc(ctr_n[loc]);
            u32 bits = __float_as_uint(scr);
            if (bits >= keymin) {
                u32 p = atomicAdd(&s_lcnt, 1u);
                if (p < (u32)CAP)
                    sk[p] = ((u64)bits << 32) | (u32)(~(loc * (u32)C_CLS + c));
            }
        }
    }
    __syncthreads();
    u32 M = s_lcnt > (u32)CAP ? (u32)CAP : s_lcnt;
    u32 cand_slots = total < (u32)K_TOP ? total : (u32)K_TOP;
    if (total < (u32)K_TOP) {                        // fallback fill list
        const u32 need = (u32)K_TOP - total;
        for (u32 basei = 0; basei < (u32)LC; basei += 1024) {
            u32 idx = basei + tid;
            u32 flag = 0;
            if (idx < (u32)LC) {
                u32 loc = idx / (u32)C_CLS;
                u32 c = idx - loc * (u32)C_CLS;
                float x = cls_n[(size_t)c * L_LOC + loc];
                flag = (sigmoidf_acc(x) > THRESH) ? 0u : 1u;
            }
            lh[tid] = flag;
            __syncthreads();
            for (u32 off = 1; off < 1024; off <<= 1) {
                u32 v = (tid >= (int)off) ? lh[tid - off] : 0u;
                __syncthreads();
                lh[tid] += v;
                __syncthreads();
            }
            u32 excl = lh[tid] - flag;
            u32 pos = s_filled + excl;
            if (flag && pos < need) fill[pos] = idx;
            __syncthreads();
            if (tid == 0) s_filled += lh[1023];
            __syncthreads();
            if (s_filled >= need) break;
        }
    }
    bitonic_desc(sk, M, tid, 1024);
    emit_rows(n, sk, cand_slots, fill, locations, breg, isz, out, tid, 1024);
}

extern "C" void kernel_launch(void* const* d_in, const int* in_sizes, int n_in,
                              void* d_out, int out_size, void* d_ws, size_t ws_size,
                              hipStream_t stream) {
    const float* locations = (const float*)d_in[0];
    const float* cls       = (const float*)d_in[1];
    const float* breg      = (const float*)d_in[2];
    const float* ctr       = (const float*)d_in[3];
    const int*   isz       = (const int*)d_in[4];
    float* out = (float*)d_out;

    char* ws = (char*)d_ws;
    u32* ws32  = (u32*)ws;
    u32* ghist = (u32*)(ws + WS_GHIST);
    u32* bcnt  = (u32*)(ws + WS_BCNT);
    u64* spec  = (u64*)(ws + WS_SPEC);

    zero_kernel<<<(ZERO_WORDS + 255) / 256, 256, 0, stream>>>(ws32);
    megaA_kernel<<<dim3(NSEG, N_IMG), 256, 0, stream>>>(cls, ctr, spec, bcnt, ghist);
    finishC_kernel<<<N_IMG, 1024, 0, stream>>>(ghist, spec, bcnt, cls, ctr,
                                               locations, breg, isz, out);
}

// Round 16
// 56.382 us; speedup vs baseline: 6.0969x; 1.0687x over previous
//
#include <hip/hip_runtime.h>
#include <math.h>

typedef unsigned int u32;
typedef unsigned long long u64;

constexpr int N_IMG = 16;
constexpr int C_CLS = 80;
constexpr int H_DIM = 160;
constexpr int W_DIM = 160;
constexpr int L_LOC = H_DIM * W_DIM;   // 25600
constexpr int LC    = L_LOC * C_CLS;   // 2048000
constexpr int K_TOP = 1000;
constexpr int NB    = 1024;            // histogram buckets: (bits-KEY_BASE)>>16
constexpr int CAP   = 2048;            // candidate cap per image (16KB LDS)
constexpr int GBUF  = 1024;            // per-segment survivor buffer (u64)
constexpr int HPAIR = 256;             // per-segment (bucket,count) pair cap
constexpr int CHUNK_L = 320;           // locations per megaA block (r12-proven)
constexpr int NSEG  = L_LOC / CHUNK_L; // 80 segments per image
constexpr int CF4   = CHUNK_L / 4;     // 80 float4 per class row
constexpr int SPAN  = 80;              // max buckets above B_SAFE (1024-948=76)
constexpr float THRESH = 0.05f;
constexpr u32 KEY_BASE = 119u << 23;   // 0x3B800000
constexpr float T0     = 0.7f;
constexpr float DELTA  = 0.05f;        // conservative slack in logit space
// buckets >= B_SAFE have lower bound > 0.7f, where spec is provably a superset
constexpr int B_SAFE  = ((0x3F340000u - KEY_BASE) >> 16);  // 948

// ---- workspace layout (bytes); NOTHING needs pre-zeroing ----
constexpr size_t WS_BCNT  = 0;                                   // u32[16*80]
constexpr size_t WS_HCNT  = 8192;                                // u32[16*80]
constexpr size_t WS_HPAIR = 16384;                               // u64[16*80*256] = 2.5MB
constexpr size_t WS_SPEC  = WS_HPAIR + (size_t)N_IMG * NSEG * HPAIR * 8;  // 10MB

__device__ inline float sigmoidf_acc(float x) { return 1.0f / (1.0f + expf(-x)); }

__device__ inline u32 score_bucket(u32 bits) {
    u32 b = (bits >= KEY_BASE) ? ((bits - KEY_BASE) >> 16) : 0u;
    return b > (u32)(NB - 1) ? (u32)(NB - 1) : b;
}

// bitonic sort (slow path only)
__device__ inline void bitonic_desc(u64* sk, u32 M, int tid, int nthr) {
    u32 n2 = 1024; while (n2 < M) n2 <<= 1;
    for (u32 i = tid; i < n2; i += nthr) if (i >= M) sk[i] = 0ull;
    __syncthreads();
    for (u32 k = 2; k <= n2; k <<= 1) {
        for (u32 j = k >> 1; j > 0; j >>= 1) {
            for (u32 i = tid; i < n2; i += nthr) {
                u32 ixj = i ^ j;
                if (ixj > i) {
                    u64 a = sk[i], b = sk[ixj];
                    bool front = ((i & k) == 0);
                    if (front ? (a < b) : (a > b)) { sk[i] = b; sk[ixj] = a; }
                }
            }
            __syncthreads();
        }
    }
}

// decode one candidate key and write its output row at rank k
__device__ inline void emit_one(int n, u64 kk, int k,
                                const float* locations, const float* breg,
                                const int* isz, float* out) {
    float* ob = out;                                  // boxes  [N,K,4]
    float* os = out + (size_t)N_IMG * K_TOP * 4;      // scores [N,K]
    float* ol = os + (size_t)N_IMG * K_TOP;           // labels [N,K]
    float* ov = ol + (size_t)N_IMG * K_TOP;           // valid  [N,K]
    const float wimg = (float)isz[n * 2 + 1];
    const float himg = (float)isz[n * 2 + 0];
    const float* rn = breg + (size_t)n * 4 * L_LOC;
    size_t slot = (size_t)n * K_TOP + k;
    u32 vb = (u32)(kk >> 32);
    u32 idx = ~(u32)(kk & 0xFFFFFFFFull);
    float val = __uint_as_float(vb);
    int loc = (int)(idx / (u32)C_CLS);
    int c = (int)(idx - (u32)loc * (u32)C_CLS);
    float lx = locations[loc * 2 + 0], ly = locations[loc * 2 + 1];
    float r0 = rn[0 * L_LOC + loc], r1 = rn[1 * L_LOC + loc];
    float r2 = rn[2 * L_LOC + loc], r3 = rn[3 * L_LOC + loc];
    float x1 = lx - r0, y1 = ly - r1, x2 = lx + r2, y2 = ly + r3;
    x1 = fminf(fmaxf(x1, 0.0f), wimg - 1.0f);
    y1 = fminf(fmaxf(y1, 0.0f), himg - 1.0f);
    x2 = fminf(fmaxf(x2, 0.0f), wimg - 1.0f);
    y2 = fminf(fmaxf(y2, 0.0f), himg - 1.0f);
    float wsz = x2 - x1 + 1.0f, hsz = y2 - y1 + 1.0f;
    bool v = (val > 0.0f) && (wsz >= 0.0f) && (hsz >= 0.0f);  // MIN_SIZE = 0
    float vf = v ? 1.0f : 0.0f;
    ob[slot * 4 + 0] = x1 * vf;
    ob[slot * 4 + 1] = y1 * vf;
    ob[slot * 4 + 2] = x2 * vf;
    ob[slot * 4 + 3] = y2 * vf;
    os[slot] = v ? sqrtf(fmaxf(val, 0.0f)) : 0.0f;
    ol[slot] = (float)(c + 1);
    ov[slot] = vf;
}

// decode + write K rows from a sorted array (slow path)
__device__ inline void emit_rows(int n, const u64* sk, u32 cand_slots, const u32* fill,
                                 const float* locations, const float* breg,
                                 const int* isz, float* out, int tid, int nthr) {
    float* ob = out;
    float* os = out + (size_t)N_IMG * K_TOP * 4;
    float* ol = os + (size_t)N_IMG * K_TOP;
    float* ov = ol + (size_t)N_IMG * K_TOP;
    for (int k = tid; k < K_TOP; k += nthr) {
        size_t slot = (size_t)n * K_TOP + k;
        if ((u32)k < cand_slots) {
            emit_one(n, sk[k], k, locations, breg, isz, out);
        } else {
            u32 fi = fill ? fill[k - (int)cand_slots] : 0u;
            ob[slot * 4 + 0] = 0.0f; ob[slot * 4 + 1] = 0.0f;
            ob[slot * 4 + 2] = 0.0f; ob[slot * 4 + 3] = 0.0f;
            os[slot] = 0.0f;
            ol[slot] = (float)((int)(fi % (u32)C_CLS) + 1);
            ov[slot] = 0.0f;
        }
    }
}

// --- kernel 1 (hot pass): r15 stream + survivor scoring; hist exported as
//     compact (bucket,count) pairs to a PRIVATE region (no global atomics,
//     no pre-zeroed state anywhere) ---
__global__ __launch_bounds__(256) void megaA_kernel(
        const float* __restrict__ cls, const float* __restrict__ ctr,
        u64* __restrict__ spec, u32* __restrict__ bcnt,
        u32* __restrict__ hcnt, u64* __restrict__ hpairs) {
    __shared__ __align__(16) float xm[CHUNK_L];
    __shared__ float sct[CHUNK_L];
    __shared__ u64 sbuf[GBUF];
    __shared__ u32 lh[NB];
    __shared__ u32 lcnt, lof, hcl;
    const int tid = threadIdx.x;
    const u32 n = blockIdx.y;
    const u32 lbase = blockIdx.x * (u32)CHUNK_L;
    for (int b = tid; b < NB; b += 256) lh[b] = 0u;
    if (tid == 0) { lcnt = 0; lof = 0; hcl = 0; }
    // prologue: per-location sigmoid(ctr) and logit threshold
    for (int i = tid; i < CHUNK_L; i += 256) {
        float s = sigmoidf_acc(ctr[(size_t)n * L_LOC + lbase + i]);
        sct[i] = s;
        float t = T0 / s;                   // need sigmoid(x) >= t for score >= T0
        xm[i] = (t >= 1.0f) ? 3.0e38f : (logf(t / (1.0f - t)) - DELTA);
    }
    __syncthreads();
    const float* base = cls + (size_t)n * LC + lbase;
    u32 m0 = 0u, m1 = 0u, m2 = 0u, m3 = 0u;
#pragma unroll
    for (int g = 0; g < 5; ++g) {
        float4 v[5]; u32 l4a[5];
#pragma unroll
        for (int k = 0; k < 5; ++k) {
            int q = g * 5 + k;
            u32 f = (u32)q * 256u + (u32)tid;        // f4 index in [0, 6400)
            u32 c = f / (u32)CF4;
            u32 l4 = f - c * (u32)CF4;
            l4a[k] = l4;
            v[k] = *reinterpret_cast<const float4*>(base + (size_t)c * L_LOC + l4 * 4u);
        }
#pragma unroll
        for (int k = 0; k < 5; ++k) {
            int q = g * 5 + k;
            float4 m4 = *reinterpret_cast<const float4*>(&xm[l4a[k] * 4u]);
            u32 nib = (v[k].x >= m4.x ? 1u : 0u) | (v[k].y >= m4.y ? 2u : 0u)
                    | (v[k].z >= m4.z ? 4u : 0u) | (v[k].w >= m4.w ? 8u : 0u);
            u32 sh = (u32)(q & 7) * 4u;
            if ((q >> 3) == 0) m0 |= nib << sh;
            else if ((q >> 3) == 1) m1 |= nib << sh;
            else if ((q >> 3) == 2) m2 |= nib << sh;
            else m3 |= nib << sh;
        }
    }
    // survivor phase (decoupled from the stream): exact score + LDS hist + append
    u32 words[4] = {m0, m1, m2, m3};
#pragma unroll
    for (int w = 0; w < 4; ++w) {
        u32 bits = words[w];
        while (bits) {
            u32 b = (u32)__ffs(bits) - 1u; bits &= bits - 1u;
            u32 q = (u32)w * 8u + (b >> 2), j = b & 3u;
            u32 f = q * 256u + (u32)tid;
            u32 c = f / (u32)CF4;
            u32 l4 = f - c * (u32)CF4;
            u32 li = l4 * 4u + j, loc = lbase + li;
            float x = base[(size_t)c * L_LOC + li];  // L3-resident re-read
            float s = sigmoidf_acc(x);               // exact reference formula
            float scr = s * sct[li];
            u32 sb = __float_as_uint(scr);
            atomicAdd(&lh[score_bucket(sb)], 1u);
            u32 p = atomicAdd(&lcnt, 1u);
            if (p < (u32)GBUF)
                sbuf[p] = ((u64)sb << 32) | (u32)(~(loc * (u32)C_CLS + c));
            else lof = 1u;
        }
    }
    __syncthreads();
    // compact non-zero hist buckets into private (bucket,count) pairs
    u64* hp = hpairs + ((size_t)n * NSEG + blockIdx.x) * HPAIR;
    for (int b = tid; b < NB; b += 256) {
        u32 v = lh[b];
        if (v) {
            u32 p = atomicAdd(&hcl, 1u);
            if (p < (u32)HPAIR) hp[p] = ((u64)(u32)b << 32) | v;
            else lof = 1u;
        }
    }
    __syncthreads();
    const u32 m_ = lcnt > (u32)GBUF ? (u32)GBUF : lcnt;
    u64* sp = spec + ((size_t)n * NSEG + blockIdx.x) * GBUF;
    for (u32 i = tid; i < m_; i += 256) sp[i] = sbuf[i];
    if (tid == 0) {
        u32 hc = hcl > (u32)HPAIR ? (u32)HPAIR : hcl;
        hcnt[n * NSEG + blockIdx.x] = hc;
        bcnt[n * NSEG + blockIdx.x] =
            m_ | ((lof || lcnt > (u32)GBUF || hcl > (u32)HPAIR) ? 0x80000000u : 0u);
    }
}

// --- kernel 2: FAST finish: pair-scatter hist -> suffix-scan -> wave-per-segment
//     filter with bucket placement -> within-bucket rank -> direct emit (NO SORT).
//     Inlined SLOW fallback (full rescan; never taken in practice). ---
__global__ __launch_bounds__(1024) void finishC_kernel(
        const u64* __restrict__ hpairs, const u32* __restrict__ hcnt,
        const u64* __restrict__ spec, const u32* __restrict__ bcnt,
        const float* __restrict__ cls, const float* __restrict__ ctr,
        const float* __restrict__ locations, const float* __restrict__ breg,
        const int* __restrict__ isz, float* __restrict__ out) {
    __shared__ u32 lh[NB];                 // raw hist -> (destructive) suffix sums
    __shared__ u64 sk[CAP];
    __shared__ u32 fill[K_TOP];
    __shared__ u32 segc[NSEG];
    __shared__ u32 hcl[NSEG];
    __shared__ u32 sfxl[SPAN + 1];
    __shared__ u32 bkc[SPAN];
    __shared__ u32 s_b, s_cnt, s_lcnt, s_filled, s_bad;
    const int n = blockIdx.x;
    const int tid = threadIdx.x;
    const int wid = tid >> 6, lane = tid & 63;       // 16 waves of 64
    if (tid == 0) { s_b = 0xFFFFFFFFu; s_lcnt = 0; s_cnt = 0; s_filled = 0; s_bad = 0; }
    lh[tid] = 0u;
    __syncthreads();
    if (tid < NSEG) {
        u32 v = bcnt[n * NSEG + tid];
        segc[tid] = v & 0x7FFFFFFFu;
        hcl[tid] = hcnt[n * NSEG + tid];
        if (v & 0x80000000u) atomicOr(&s_bad, 1u);
    }
    __syncthreads();
    // rebuild hist from compact pairs: one WAVE per segment, 16 concurrent
    const u64* hpn = hpairs + (size_t)n * NSEG * HPAIR;
    for (int sr = 0; sr < NSEG; sr += 16) {
        int s2 = sr + wid;                            // NSEG % 16 == 0
        u32 hc = hcl[s2];
        const u64* hp = hpn + (size_t)s2 * HPAIR;
        for (u32 i = lane; i < hc; i += 64) {
            u64 pr = hp[i];
            atomicAdd(&lh[(u32)(pr >> 32)], (u32)pr);
        }
    }
    __syncthreads();
    // suffix sums: lh[b] = count with bucket >= b (r12-proven)
    for (u32 off = 1; off < (u32)NB; off <<= 1) {
        u32 add = (tid + off < (u32)NB) ? lh[tid + off] : 0u;
        __syncthreads();
        lh[tid] += add;
        __syncthreads();
    }
    if (lh[tid] >= (u32)K_TOP && (tid == NB - 1 || lh[tid + 1] < (u32)K_TOP)) {
        s_b = (u32)tid; s_cnt = lh[tid];
    }
    __syncthreads();
    const u32 bstar = s_b;
    const u32 cnt_at = s_cnt;
    bool fastok = (s_bad == 0u) && (bstar != 0xFFFFFFFFu) &&
                  (bstar >= (u32)B_SAFE) && (cnt_at <= (u32)CAP);
    const u64* spn = spec + (size_t)n * NSEG * GBUF;
    if (fastok) {
        const u32 span = (u32)NB - bstar;            // <= 76
        const u32 keymin = KEY_BASE + (bstar << 16);
        if (tid <= (int)span) sfxl[tid] = (bstar + (u32)tid < (u32)NB) ? lh[bstar + tid] : 0u;
        if (tid < (int)span) bkc[tid] = 0u;
        __syncthreads();
        // wave-per-segment filter + bucket-grouped placement
        for (int sr = 0; sr < NSEG; sr += 16) {
            int s2 = sr + wid;
            u32 cnt = segc[s2];
            const u64* sp = spn + (size_t)s2 * GBUF;
            for (u32 i = lane; i < cnt; i += 64) {
                u64 e = sp[i];
                u32 bits = (u32)(e >> 32);
                if (bits >= keymin) {
                    u32 t = score_bucket(bits) - bstar;
                    u32 pos = sfxl[t + 1] + atomicAdd(&bkc[t], 1u);
                    if (pos < (u32)CAP) sk[pos] = e;
                }
            }
        }
        __syncthreads();
        // within-bucket rank + direct emit (keys unique -> ranks unique, complete)
        for (u32 p = tid; p < cnt_at; p += 1024) {
            u64 e = sk[p];
            u32 t = score_bucket((u32)(e >> 32)) - bstar;
            u32 r = sfxl[t + 1];
            const u32 qe = sfxl[t];
            for (u32 q = sfxl[t + 1]; q < qe; ++q) r += (sk[q] > e) ? 1u : 0u;
            if (r < (u32)K_TOP)
                emit_one(n, e, (int)r, locations, breg, isz, out);
        }
        return;
    }
    // ---------- SLOW path (gated; full per-image pipeline; r12-proven) ----------
    lh[tid] = 0u;
    if (tid == 0) { s_b = 0xFFFFFFFFu; s_lcnt = 0; s_filled = 0; }
    __syncthreads();
    const float* cls_n = cls + (size_t)n * LC;
    const float* ctr_n = ctr + (size_t)n * L_LOC;
    for (u32 f = tid; f < (u32)LC; f += 1024) {
        float s = sigmoidf_acc(cls_n[f]);
        if (s > THRESH) {
            float scr = s * sigmoidf_acc(ctr_n[f % (u32)L_LOC]);
            atomicAdd(&lh[score_bucket(__float_as_uint(scr))], 1u);
        }
    }
    __syncthreads();
    for (u32 off = 1; off < (u32)NB; off <<= 1) {
        u32 add = (tid + off < (u32)NB) ? lh[tid + off] : 0u;
        __syncthreads();
        lh[tid] += add;
        __syncthreads();
    }
    if (lh[tid] >= (u32)K_TOP && (tid == NB - 1 || lh[tid + 1] < (u32)K_TOP))
        s_b = (u32)tid;
    __syncthreads();
    const u32 total = lh[0];
    const u32 keymin = (s_b != 0xFFFFFFFFu) ? (KEY_BASE + (s_b << 16)) : 0u;
    __syncthreads();
    for (u32 f = tid; f < (u32)LC; f += 1024) {
        float s = sigmoidf_acc(cls_n[f]);
        if (s > THRESH) {
            u32 loc = f % (u32)L_LOC;
            u32 c = f / (u32)L_LOC;
            float scr = s * sigmoidf_acc(ctr_n[loc]);
            u32 bits = __float_as_uint(scr);
            if (bits >= keymin) {
                u32 p = atomicAdd(&s_lcnt, 1u);
                if (p < (u32)CAP)
                    sk[p] = ((u64)bits << 32) | (u32)(~(loc * (u32)C_CLS + c));
            }
        }
    }
    __syncthreads();
    u32 M = s_lcnt > (u32)CAP ? (u32)CAP : s_lcnt;
    u32 cand_slots = total < (u32)K_TOP ? total : (u32)K_TOP;
    if (total < (u32)K_TOP) {                        // fallback fill list
        const u32 need = (u32)K_TOP - total;
        for (u32 basei = 0; basei < (u32)LC; basei += 1024) {
            u32 idx = basei + tid;
            u32 flag = 0;
            if (idx < (u32)LC) {
                u32 loc = idx / (u32)C_CLS;
                u32 c = idx - loc * (u32)C_CLS;
                float x = cls_n[(size_t)c * L_LOC + loc];
                flag = (sigmoidf_acc(x) > THRESH) ? 0u : 1u;
            }
            lh[tid] = flag;
            __syncthreads();
            for (u32 off = 1; off < 1024; off <<= 1) {
                u32 v = (tid >= (int)off) ? lh[tid - off] : 0u;
                __syncthreads();
                lh[tid] += v;
                __syncthreads();
            }
            u32 excl = lh[tid] - flag;
            u32 pos = s_filled + excl;
            if (flag && pos < need) fill[pos] = idx;
            __syncthreads();
            if (tid == 0) s_filled += lh[1023];
            __syncthreads();
            if (s_filled >= need) break;
        }
    }
    bitonic_desc(sk, M, tid, 1024);
    emit_rows(n, sk, cand_slots, fill, locations, breg, isz, out, tid, 1024);
}

extern "C" void kernel_launch(void* const* d_in, const int* in_sizes, int n_in,
                              void* d_out, int out_size, void* d_ws, size_t ws_size,
                              hipStream_t stream) {
    const float* locations = (const float*)d_in[0];
    const float* cls       = (const float*)d_in[1];
    const float* breg      = (const float*)d_in[2];
    const float* ctr       = (const float*)d_in[3];
    const int*   isz       = (const int*)d_in[4];
    float* out = (float*)d_out;

    char* ws = (char*)d_ws;
    u32* bcnt   = (u32*)(ws + WS_BCNT);
    u32* hcnt   = (u32*)(ws + WS_HCNT);
    u64* hpairs = (u64*)(ws + WS_HPAIR);
    u64* spec   = (u64*)(ws + WS_SPEC);

    megaA_kernel<<<dim3(NSEG, N_IMG), 256, 0, stream>>>(cls, ctr, spec, bcnt, hcnt, hpairs);
    finishC_kernel<<<N_IMG, 1024, 0, stream>>>(hpairs, hcnt, spec, bcnt, cls, ctr,
                                               locations, breg, isz, out);
}